// Round 2
// baseline (561.280 us; speedup 1.0000x reference)
//
#include <hip/hip_runtime.h>
#include <math.h>

#define C 100
#define NBINS 15
#define NEG4 make_float4(-INFINITY, -INFINITY, -INFINITY, -INFINITY)

// Pass 1: each 32-lane group handles a PAIR of adjacent rows (800 B contiguous)
// per iteration, with register double-buffer prefetch of the next pair + labels
// so ~4 loads stay in flight per group (MLP fix vs R1's 1-outstanding-load).
__global__ __launch_bounds__(256) void ece_pass1(
    const float* __restrict__ probs, const int* __restrict__ labels,
    float* __restrict__ partials, int N, int G) {
  __shared__ float sbin[2 * NBINS];  // [0..14]=sum conf, [15..29]=sum correct
  if (threadIdx.x < 2 * NBINS) sbin[threadIdx.x] = 0.0f;
  __syncthreads();

  const int lane   = threadIdx.x & 31;
  const int group  = threadIdx.x >> 5;
  const int gpb    = blockDim.x >> 5;      // 8 groups / block
  const int stride = G * gpb;              // pairs per grid step
  const int nPairs = (N + 1) >> 1;

  int p = blockIdx.x * gpb + group;
  bool valid = p < nPairs;

  // current pair: rows 2p (a0) and 2p+1 (a1); lanes 0,1 hold the two labels
  float4 a0 = NEG4, a1 = NEG4;
  int lab = -1;
  if (valid) {
    const float4* rp = (const float4*)(probs + (size_t)p * (2 * C));
    if (lane < 25) {
      a0 = rp[lane];
      if ((2 * p + 1) < N) a1 = rp[lane + 25];
    }
    if (lane < 2 && (2 * p + lane) < N) lab = labels[2 * p + lane];
  }

  while (valid) {
    const int  pn     = p + stride;
    const bool nvalid = pn < nPairs;

    // ---- prefetch next pair (independent of current processing) ----
    float4 b0 = NEG4, b1 = NEG4;
    int nlab = -1;
    if (nvalid) {
      const float4* rp = (const float4*)(probs + (size_t)pn * (2 * C));
      if (lane < 25) {
        b0 = rp[lane];
        if ((2 * pn + 1) < N) b1 = rp[lane + 25];
      }
      if (lane < 2 && (2 * pn + lane) < N) nlab = labels[2 * pn + lane];
    }

    // ---- process current pair: two interleaved independent chains ----
    float mv0 = a0.x; int mi0 = 4 * lane;
    if (a0.y > mv0) { mv0 = a0.y; mi0 = 4 * lane + 1; }
    if (a0.z > mv0) { mv0 = a0.z; mi0 = 4 * lane + 2; }
    if (a0.w > mv0) { mv0 = a0.w; mi0 = 4 * lane + 3; }
    float mv1 = a1.x; int mi1 = 4 * lane;
    if (a1.y > mv1) { mv1 = a1.y; mi1 = 4 * lane + 1; }
    if (a1.z > mv1) { mv1 = a1.z; mi1 = 4 * lane + 2; }
    if (a1.w > mv1) { mv1 = a1.w; mi1 = 4 * lane + 3; }
    if (lane >= 25) { mi0 = 0x7fffffff; mi1 = 0x7fffffff; }

    #pragma unroll
    for (int m = 16; m >= 1; m >>= 1) {
      float o0 = __shfl_xor(mv0, m); int i0 = __shfl_xor(mi0, m);
      float o1 = __shfl_xor(mv1, m); int i1 = __shfl_xor(mi1, m);
      if (o0 > mv0 || (o0 == mv0 && i0 < mi0)) { mv0 = o0; mi0 = i0; }
      if (o1 > mv1 || (o1 == mv1 && i1 < mi1)) { mv1 = o1; mi1 = i1; }
    }

    float se0 = 0.0f, se1 = 0.0f;
    if (lane < 25) {
      se0 = __expf(a0.x - mv0) + __expf(a0.y - mv0) +
            __expf(a0.z - mv0) + __expf(a0.w - mv0);
      se1 = __expf(a1.x - mv1) + __expf(a1.y - mv1) +
            __expf(a1.z - mv1) + __expf(a1.w - mv1);
    }
    #pragma unroll
    for (int m = 16; m >= 1; m >>= 1) {
      se0 += __shfl_xor(se0, m);
      se1 += __shfl_xor(se1, m);
    }

    // epilogue: lane 0 handles row 2p, lane 1 handles row 2p+1 (one inst path)
    if (lane < 2 && (2 * p + lane) < N) {
      float conf = (lane == 0) ? (1.0f / se0) : (1.0f / se1);
      int   pred = (lane == 0) ? mi0 : mi1;
      // bin = clip(count(linspace(0,1,16) < conf) - 1, 0, 14)  (matches
      // searchsorted side='left' - 1; verified absmax=0 in R1)
      int cnt = 0;
      #pragma unroll
      for (int i = 0; i <= NBINS; ++i)
        cnt += (((float)i / (float)NBINS) < conf) ? 1 : 0;
      int bin = cnt - 1;
      bin = bin < 0 ? 0 : (bin > NBINS - 1 ? NBINS - 1 : bin);
      atomicAdd(&sbin[bin], conf);
      atomicAdd(&sbin[NBINS + bin], (pred == lab) ? 1.0f : 0.0f);
    }

    a0 = b0; a1 = b1; lab = nlab; p = pn; valid = nvalid;
  }

  __syncthreads();
  // column-major partials: partials[col*G + block], col in [0,30)
  if (threadIdx.x < 2 * NBINS)
    partials[(size_t)threadIdx.x * G + blockIdx.x] = sbin[threadIdx.x];
}

// Pass 2: single block; 32-lane group g reduces column g over G blocks (double),
// then thread 0 computes sum_b |sum_conf_b - sum_corr_b| / N.
__global__ __launch_bounds__(1024) void ece_pass2(
    const float* __restrict__ partials, float* __restrict__ out, int G, int N) {
  __shared__ double cols[32];
  const int lane = threadIdx.x & 31;
  const int grp  = threadIdx.x >> 5;   // 32 groups; 30 used
  double s = 0.0;
  if (grp < 2 * NBINS) {
    for (int g = lane; g < G; g += 32)
      s += (double)partials[(size_t)grp * G + g];
  }
  #pragma unroll
  for (int m = 16; m >= 1; m >>= 1) s += __shfl_xor(s, m);
  if (lane == 0) cols[grp] = s;
  __syncthreads();
  if (threadIdx.x == 0) {
    double e = 0.0;
    for (int b = 0; b < NBINS; ++b) e += fabs(cols[b] - cols[NBINS + b]);
    out[0] = (float)(e / (double)N);
  }
}

extern "C" void kernel_launch(void* const* d_in, const int* in_sizes, int n_in,
                              void* d_out, int out_size, void* d_ws, size_t ws_size,
                              hipStream_t stream) {
  const float* probs    = (const float*)d_in[0];
  const int*   labels   = (const int*)d_in[1];
  float*       out      = (float*)d_out;
  float*       partials = (float*)d_ws;

  const int N = in_sizes[1];            // rows (labels count)

  int G = 2048;                         // 2048 blocks * 4 waves -> 32 waves/CU
  size_t need = (size_t)2 * NBINS * G * sizeof(float);
  if (ws_size < need) {
    G = (int)(ws_size / ((size_t)2 * NBINS * sizeof(float)));
    if (G < 1) G = 1;
  }

  ece_pass1<<<G, 256, 0, stream>>>(probs, labels, partials, N, G);
  ece_pass2<<<1, 1024, 0, stream>>>(partials, out, G, N);
}